// Round 4
// baseline (664.048 us; speedup 1.0000x reference)
//
#include <hip/hip_runtime.h>

#define DIM   2048
#define LSEQ  4096
#define BATCH 4
#define NTOK  (BATCH*LSEQ)        // 16384
#define NCH   16
#define CHL   (LSEQ/NCH)          // 256
#define PI_F  3.14159265358979f
#define NT    (DIM/64)            // 32 K-tiles of 64

typedef __bf16 bf16x8 __attribute__((ext_vector_type(8)));
typedef float  f32x4  __attribute__((ext_vector_type(4)));
typedef float  f32x8  __attribute__((ext_vector_type(8)));
typedef unsigned short ushort4_t __attribute__((ext_vector_type(4)));
typedef unsigned short ushort8 __attribute__((ext_vector_type(8)));

__device__ __forceinline__ unsigned short f2bf(float f) {
    unsigned int u = __float_as_uint(f);
    u += 0x7fffu + ((u >> 16) & 1u);       // round-to-nearest-even
    return (unsigned short)(u >> 16);
}

__device__ __forceinline__ void gload_lds16(const void* g, void* l) {
    __builtin_amdgcn_global_load_lds(
        (const __attribute__((address_space(1))) void*)g,
        (__attribute__((address_space(3))) void*)l, 16, 0, 0);
}

// ---------------- W [K][N] fp32 -> W^T [N][K] bf16 ----------------
__global__ __launch_bounds__(256) void k_transpose(const float* __restrict__ src,
                                                   unsigned short* __restrict__ dst) {
    __shared__ float tile[32][33];
    int tx = threadIdx.x, ty = threadIdx.y;
    int k0 = blockIdx.y * 32, n0 = blockIdx.x * 32;
#pragma unroll
    for (int r = 0; r < 4; r++)
        tile[ty + r * 8][tx] = src[(size_t)(k0 + ty + r * 8) * DIM + n0 + tx];
    __syncthreads();
#pragma unroll
    for (int r = 0; r < 4; r++)
        dst[(size_t)(n0 + ty + r * 8) * DIM + k0 + tx] = f2bf(tile[tx][ty + r * 8]);
}

// ---- per-token scalar s; one token per WAVE, no barriers; fused x->bf16 ----
// Reduce: vector-halving butterfly (16 accs -> 1 scalar/lane in 4 stages),
// then xor16/xor32 scalar adds; nonlinearity distributed over 8 even lanes.
__global__ __launch_bounds__(256) void k_sproj(const float* __restrict__ x,
                                               const float* __restrict__ Wp,
                                               const float* __restrict__ bp,
                                               const float* __restrict__ Wa,
                                               const float* __restrict__ ba,
                                               float* __restrict__ s,
                                               unsigned short* __restrict__ xbf) {
    const int t = threadIdx.x;
    const int w = t >> 6, l = t & 63;
    const int tok = blockIdx.x * 4 + w;
    const float* xr = x + (size_t)tok * DIM;
    unsigned short* xbr = xbf + (size_t)tok * DIM;

    float acc[16];
#pragma unroll
    for (int p = 0; p < 16; p++) acc[p] = 0.f;

#pragma unroll
    for (int e = 0; e < 8; e++) {
        int idx = e * 256 + l * 4;
        f32x4 xv = *(const f32x4*)(xr + idx);
        ushort4_t xo;
        xo[0] = f2bf(xv[0]); xo[1] = f2bf(xv[1]); xo[2] = f2bf(xv[2]); xo[3] = f2bf(xv[3]);
        *(ushort4_t*)(xbr + idx) = xo;
#pragma unroll
        for (int j = 0; j < 4; j++) {
            f32x8 wpv = *(const f32x8*)(Wp + (size_t)(idx + j) * 8);
            f32x8 wav = *(const f32x8*)(Wa + (size_t)(idx + j) * 8);
#pragma unroll
            for (int c = 0; c < 8; c++) {
                acc[c]     += xv[j] * wpv[c];
                acc[8 + c] += xv[j] * wav[c];
            }
        }
    }

    // vector-halving butterfly: stage k (xor 1<<k) halves the live vector.
    // lane keeps low half if ((l>>k)&1)==0, sends the other half.
#pragma unroll
    for (int k = 0; k < 4; k++) {
        const int n2 = 8 >> k;              // half-length at this stage
        const bool hi = (l >> k) & 1;
#pragma unroll
        for (int i = 0; i < 8; i++) {
            if (i < n2) {
                float send = hi ? acc[i] : acc[i + n2];
                float recv = __shfl_xor(send, 1 << k);
                acc[i] = (hi ? acc[i + n2] : acc[i]) + recv;
            }
        }
    }
    float z = acc[0];
    z += __shfl_xor(z, 16);
    z += __shfl_xor(z, 32);
    // lane l holds element idx = bitrev4(l&15): bit3=l0 (0=phase,1=amp),
    // p = rev3((l>>1)&7). Even lane: zp; odd lane (l|1): za, same p.
    const int p = (((l >> 1) & 1) << 2) | (((l >> 2) & 1) << 1) | ((l >> 3) & 1);
    float zpair = __shfl_xor(z, 1);
    // even lanes compute the real term; odd lanes compute garbage (masked out)
    float zp = z + bp[p];
    float za = zpair + ba[p];
    float ph = tanhf(zp) * PI_F;
    float amp = (za > 20.f ? za : log1pf(expf(za))) + 0.1f;
    float term = (l & 1) ? 0.f : (cosf(ph) + sinf(ph)) * amp;
    // sum the 8 even lanes of the 16-group (xor by even masks keeps parity)
    term += __shfl_xor(term, 2);
    term += __shfl_xor(term, 4);
    term += __shfl_xor(term, 8);
    if (l == 0) s[tok] = term;
}

// ---------------- 256x256 8-phase bf16 MFMA GEMM (T1+T2+T3+T4+T5) ----------------
// A: [M][2048] bf16; Bt: [2048][2048] bf16 (B^T). 512 threads = 8 waves (2M x 4N).
// LDS [slot][kh][256 rows][32 k]; 16B-unit XOR swizzle: phys_q = q ^ ((row>>1)&3).
// Stage side keeps LDS dest linear (global_load_lds) and applies the inverse
// permutation to the global SOURCE k-chunk (rule: both-sides-or-neither).
__device__ __forceinline__ void stage_unit(const unsigned short* __restrict__ src,
                                           unsigned short* dst, int tid) {
    gload_lds16(src,                     dst + tid * 8);
    gload_lds16(src + (size_t)128 * DIM, dst + (tid + 512) * 8);
}

template <int EPI>
__global__ __launch_bounds__(512, 2) void k_gemm256(const unsigned short* __restrict__ A,
                                                    const unsigned short* __restrict__ Bt,
                                                    const float* __restrict__ bias,
                                                    const float* __restrict__ sc,
                                                    const float* __restrict__ resid,
                                                    float* __restrict__ C) {
    __shared__ __align__(16) unsigned short As[2][2][256 * 32];
    __shared__ __align__(16) unsigned short Bs[2][2][256 * 32];
    const int tid = threadIdx.x;
    const int w = tid >> 6, lane = tid & 63;
    const int wm = w >> 2, wn = w & 3;
    const int r16 = lane & 15, q = lane >> 4;

    int bid = blockIdx.x;
    int wgs = (bid & 7) * 64 + (bid >> 3);        // bijective XCD swizzle (512 % 8 == 0)
    int tm = wgs >> 3, tn = wgs & 7;
    int brow = tm * 256, bcol = tn * 256;

    // staging source: thread tid fills phys 16B-unit 'tid' (row=tid>>2, physq=tid&3),
    // which logically holds k-chunk (tid&3) ^ ((tid>>3)&3).
    const int kq = ((tid & 3) ^ ((tid >> 3) & 3)) * 8;
    const unsigned short* pA = A  + (size_t)(brow + (tid >> 2)) * DIM + kq;
    const unsigned short* pB = Bt + (size_t)(bcol + (tid >> 2)) * DIM + kq;

    // fragment read: swizzled q (row offsets are multiples of 16 -> swizzle dep on r16 only)
    const int qs8 = (q ^ ((r16 >> 1) & 3)) * 8;
    const int offA = (wm * 128 + r16) * 32 + qs8;
    const int offB = (wn * 64  + r16) * 32 + qs8;

    f32x4 acc[8][4] = {};

    // prologue: A-K0(0), B-K0(0), A-K1(0), B-K1(0), A-K0(1) = 10 loads in flight
    stage_unit(pA,      &As[0][0][0], tid);
    stage_unit(pB,      &Bs[0][0][0], tid);
    stage_unit(pA + 32, &As[0][1][0], tid);
    stage_unit(pB + 32, &Bs[0][1][0], tid);
    stage_unit(pA + 64, &As[1][0][0], tid);
    asm volatile("s_waitcnt vmcnt(6)" ::: "memory");    // K0(0) pair landed
    __builtin_amdgcn_s_barrier();

    for (int t = 0; t < NT; ++t) {
        const int s = t & 1;
        unsigned short* A0 = &As[s][0][0];
        unsigned short* A1 = &As[s][1][0];
        unsigned short* B0 = &Bs[s][0][0];
        unsigned short* B1 = &Bs[s][1][0];
        unsigned short* nA1 = &As[s ^ 1][1][0];
        unsigned short* nB0 = &Bs[s ^ 1][0][0];
        unsigned short* nB1 = &Bs[s ^ 1][1][0];
        const unsigned short* pAn = pA + (t + 1) * 64;  // phantom tail reads stay in ws
        const unsigned short* pBn = pB + (t + 1) * 64;

        bf16x8 aF[4], bF[4];
        // ---- phase 0: (C0, K0) ----
#pragma unroll
        for (int i = 0; i < 4; i++) aF[i] = *(const bf16x8*)(A0 + offA + i * 512);
#pragma unroll
        for (int i = 0; i < 4; i++) bF[i] = *(const bf16x8*)(B0 + offB + i * 512);
        stage_unit(pBn, nB0, tid);
        __builtin_amdgcn_s_barrier();
        __builtin_amdgcn_s_setprio(1);
#pragma unroll
        for (int i = 0; i < 4; i++)
#pragma unroll
            for (int n = 0; n < 4; n++)
                acc[i][n] = __builtin_amdgcn_mfma_f32_16x16x32_bf16(aF[i], bF[n], acc[i][n], 0, 0, 0);
        __builtin_amdgcn_s_setprio(0);
        __builtin_amdgcn_s_barrier();

        // ---- phase 1: (C1, K0), B frags reused from registers ----
#pragma unroll
        for (int i = 0; i < 4; i++) aF[i] = *(const bf16x8*)(A0 + offA + 2048 + i * 512);
        stage_unit(pAn + 32, nA1, tid);
        __builtin_amdgcn_s_barrier();
        __builtin_amdgcn_s_setprio(1);
#pragma unroll
        for (int i = 0; i < 4; i++)
#pragma unroll
            for (int n = 0; n < 4; n++)
                acc[4 + i][n] = __builtin_amdgcn_mfma_f32_16x16x32_bf16(aF[i], bF[n], acc[4 + i][n], 0, 0, 0);
        __builtin_amdgcn_s_setprio(0);
        asm volatile("s_waitcnt vmcnt(6)" ::: "memory"); // K1(t) pair landed before phase 2
        __builtin_amdgcn_s_barrier();

        // ---- phase 2: (C0, K1) ----
#pragma unroll
        for (int i = 0; i < 4; i++) aF[i] = *(const bf16x8*)(A1 + offA + i * 512);
#pragma unroll
        for (int i = 0; i < 4; i++) bF[i] = *(const bf16x8*)(B1 + offB + i * 512);
        stage_unit(pBn + 32, nB1, tid);
        __builtin_amdgcn_s_barrier();
        __builtin_amdgcn_s_setprio(1);
#pragma unroll
        for (int i = 0; i < 4; i++)
#pragma unroll
            for (int n = 0; n < 4; n++)
                acc[i][n] = __builtin_amdgcn_mfma_f32_16x16x32_bf16(aF[i], bF[n], acc[i][n], 0, 0, 0);
        __builtin_amdgcn_s_setprio(0);
        __builtin_amdgcn_s_barrier();

        // ---- phase 3: (C1, K1) ----
#pragma unroll
        for (int i = 0; i < 4; i++) aF[i] = *(const bf16x8*)(A1 + offA + 2048 + i * 512);
        stage_unit(pA + (t + 2) * 64, A0, tid);          // overwrite own slot K0 (last read phase 1)
        __builtin_amdgcn_s_barrier();
        __builtin_amdgcn_s_setprio(1);
#pragma unroll
        for (int i = 0; i < 4; i++)
#pragma unroll
            for (int n = 0; n < 4; n++)
                acc[4 + i][n] = __builtin_amdgcn_mfma_f32_16x16x32_bf16(aF[i], bF[n], acc[4 + i][n], 0, 0, 0);
        __builtin_amdgcn_s_setprio(0);
        asm volatile("s_waitcnt vmcnt(6)" ::: "memory"); // K0(t+1) pair landed before next phase 0
        __builtin_amdgcn_s_barrier();
    }

    // epilogue: frag row = q*4+j, col = r16 (verified convention)
#pragma unroll
    for (int mf = 0; mf < 8; mf++) {
        int r0 = brow + wm * 128 + mf * 16 + q * 4;
#pragma unroll
        for (int nf = 0; nf < 4; nf++) {
            int c = bcol + wn * 64 + nf * 16 + r16;
            float bc = bias[c];
#pragma unroll
            for (int j = 0; j < 4; j++) {
                int r = r0 + j;
                float v = acc[mf][nf][j] + bc;
                if (EPI == 0) v *= sc[r];
                else          v += resid[(size_t)r * DIM + c];
                C[(size_t)r * DIM + c] = v;
            }
        }
    }
}

// ---------------- cumsum over L (3-pass chunked scan, in-place on bound) ----------------
__global__ __launch_bounds__(256) void k_scan_partial(const float* __restrict__ bound,
                                                      float* __restrict__ part) {
    int tid = blockIdx.x * 256 + threadIdx.x;  // (b, ch, d)
    int d = tid & (DIM - 1);
    int ch = (tid >> 11) & (NCH - 1);
    int b = tid >> 15;
    const float* p = bound + ((size_t)b * LSEQ + (size_t)ch * CHL) * DIM + d;
    float sum = 0.f;
    for (int i = 0; i < CHL; i++) sum += p[(size_t)i * DIM];
    part[tid] = sum;
}

__global__ __launch_bounds__(256) void k_scan_offsets(float* __restrict__ part) {
    int tid = blockIdx.x * 256 + threadIdx.x;  // (b, d)
    int d = tid & (DIM - 1);
    int b = tid >> 11;
    float run = 0.f;
    for (int ch = 0; ch < NCH; ch++) {
        size_t idx = ((size_t)b * NCH + ch) * DIM + d;
        float v = part[idx];
        part[idx] = run;
        run += v;
    }
}

__global__ __launch_bounds__(256) void k_scan_apply(float* __restrict__ bound,
                                                    const float* __restrict__ part) {
    int tid = blockIdx.x * 256 + threadIdx.x;
    int d = tid & (DIM - 1);
    int ch = (tid >> 11) & (NCH - 1);
    int b = tid >> 15;
    float run = part[tid];
    float* p = bound + ((size_t)b * LSEQ + (size_t)ch * CHL) * DIM + d;
    for (int i = 0; i < CHL; i++) { run += p[(size_t)i * DIM]; p[(size_t)i * DIM] = run; }
}

// ---------------- LayerNorm(retrieved/64) -> h bf16 ----------------
__global__ __launch_bounds__(256) void k_lnorm(const float* __restrict__ ret,
                                               const float* __restrict__ g,
                                               const float* __restrict__ bta,
                                               unsigned short* __restrict__ h) {
    int row = blockIdx.x, t = threadIdx.x;
    const float4* r4 = (const float4*)(ret + (size_t)row * DIM);
    float4 v0 = r4[2 * t], v1 = r4[2 * t + 1];
    const float scl = 1.0f / 64.0f;   // 1/sqrt(L)
    v0.x *= scl; v0.y *= scl; v0.z *= scl; v0.w *= scl;
    v1.x *= scl; v1.y *= scl; v1.z *= scl; v1.w *= scl;
    float sum = v0.x + v0.y + v0.z + v0.w + v1.x + v1.y + v1.z + v1.w;
    float ss  = v0.x*v0.x + v0.y*v0.y + v0.z*v0.z + v0.w*v0.w
              + v1.x*v1.x + v1.y*v1.y + v1.z*v1.z + v1.w*v1.w;
#pragma unroll
    for (int off = 32; off; off >>= 1) { sum += __shfl_down(sum, off); ss += __shfl_down(ss, off); }
    __shared__ float red[4][2];
    __shared__ float mu_s, rstd_s;
    int w = t >> 6, lane = t & 63;
    if (lane == 0) { red[w][0] = sum; red[w][1] = ss; }
    __syncthreads();
    if (t == 0) {
        float S = red[0][0] + red[1][0] + red[2][0] + red[3][0];
        float Q = red[0][1] + red[1][1] + red[2][1] + red[3][1];
        float mu = S / DIM;
        float var = Q / DIM - mu * mu;
        mu_s = mu; rstd_s = rsqrtf(var + 1e-5f);
    }
    __syncthreads();
    float mu = mu_s, rstd = rstd_s;
    f32x8 gv = *(const f32x8*)(g + t * 8);
    f32x8 bv = *(const f32x8*)(bta + t * 8);
    float vv[8] = { v0.x, v0.y, v0.z, v0.w, v1.x, v1.y, v1.z, v1.w };
    ushort8 o;
#pragma unroll
    for (int j = 0; j < 8; j++) o[j] = f2bf((vv[j] - mu) * rstd * gv[j] + bv[j]);
    *(ushort8*)(h + (size_t)row * DIM + t * 8) = o;
}

extern "C" void kernel_launch(void* const* d_in, const int* in_sizes, int n_in,
                              void* d_out, int out_size, void* d_ws, size_t ws_size,
                              hipStream_t stream) {
    const float* x   = (const float*)d_in[0];
    const float* Wp  = (const float*)d_in[1];
    const float* bp  = (const float*)d_in[2];
    const float* Wa  = (const float*)d_in[3];
    const float* ba  = (const float*)d_in[4];
    const float* Wv  = (const float*)d_in[5];
    const float* bv  = (const float*)d_in[6];
    const float* lng = (const float*)d_in[7];
    const float* lnb = (const float*)d_in[8];
    const float* Wo  = (const float*)d_in[9];
    const float* bo  = (const float*)d_in[10];
    float* out = (float*)d_out;

    char* ws = (char*)d_ws;
    unsigned short* x_bf = (unsigned short*)ws; ws += (size_t)NTOK * DIM * 2;   // reused as h
    unsigned short* WvT  = (unsigned short*)ws; ws += (size_t)DIM * DIM * 2;
    unsigned short* WoT  = (unsigned short*)ws; ws += (size_t)DIM * DIM * 2;
    float* svec          = (float*)ws;          ws += (size_t)NTOK * 4;
    float* bound         = (float*)ws;          ws += (size_t)NTOK * DIM * 4;
    float* part          = (float*)ws;          ws += (size_t)BATCH * NCH * DIM * 4;

    dim3 tb(32, 8);
    k_transpose<<<dim3(64, 64), tb, 0, stream>>>(Wv, WvT);
    k_transpose<<<dim3(64, 64), tb, 0, stream>>>(Wo, WoT);
    k_sproj<<<NTOK / 4, 256, 0, stream>>>(x, Wp, bp, Wa, ba, svec, x_bf);

    k_gemm256<0><<<512, 512, 0, stream>>>(x_bf, WvT, bv, svec, nullptr, bound);

    k_scan_partial<<<BATCH * NCH * DIM / 256, 256, 0, stream>>>(bound, part);
    k_scan_offsets<<<BATCH * DIM / 256, 256, 0, stream>>>(part);
    k_scan_apply<<<BATCH * NCH * DIM / 256, 256, 0, stream>>>(bound, part);

    k_lnorm<<<NTOK, 256, 0, stream>>>(bound, lng, lnb, x_bf);   // h reuses x_bf buffer

    k_gemm256<1><<<512, 512, 0, stream>>>(x_bf, WoT, bo, nullptr, x, out);
}

// Round 5
// 433.528 us; speedup vs baseline: 1.5317x; 1.5317x over previous
//
#include <hip/hip_runtime.h>

#define DIM   2048
#define LSEQ  4096
#define BATCH 4
#define NTOK  (BATCH*LSEQ)        // 16384
#define NCH   16
#define CHL   (LSEQ/NCH)          // 256
#define PI_F  3.14159265358979f
#define NT    (DIM/64)            // 32 K-tiles of 64

typedef __bf16 bf16x8 __attribute__((ext_vector_type(8)));
typedef float  f32x4  __attribute__((ext_vector_type(4)));
typedef float  f32x8  __attribute__((ext_vector_type(8)));
typedef unsigned short ushort8 __attribute__((ext_vector_type(8)));

__device__ __forceinline__ unsigned short f2bf(float f) {
    unsigned int u = __float_as_uint(f);
    u += 0x7fffu + ((u >> 16) & 1u);       // round-to-nearest-even
    return (unsigned short)(u >> 16);
}

__device__ __forceinline__ void gload_lds16(const void* g, void* l) {
    __builtin_amdgcn_global_load_lds(
        (const __attribute__((address_space(1))) void*)g,
        (__attribute__((address_space(3))) void*)l, 16, 0, 0);
}

// ---------------- W [K][N] fp32 -> W^T [N][K] bf16 ----------------
__global__ __launch_bounds__(256) void k_transpose(const float* __restrict__ src,
                                                   unsigned short* __restrict__ dst) {
    __shared__ float tile[32][33];
    int tx = threadIdx.x, ty = threadIdx.y;
    int k0 = blockIdx.y * 32, n0 = blockIdx.x * 32;
#pragma unroll
    for (int r = 0; r < 4; r++)
        tile[ty + r * 8][tx] = src[(size_t)(k0 + ty + r * 8) * DIM + n0 + tx];
    __syncthreads();
#pragma unroll
    for (int r = 0; r < 4; r++)
        dst[(size_t)(n0 + ty + r * 8) * DIM + k0 + tx] = f2bf(tile[tx][ty + r * 8]);
}

// ---------------- W_paT[16][2048] bf16 : rows 0..7 = Wp cols, 8..15 = Wa cols ----------------
__global__ __launch_bounds__(256) void k_prep_wpa(const float* __restrict__ Wp,
                                                  const float* __restrict__ Wa,
                                                  unsigned short* __restrict__ WpaT) {
    int idx = blockIdx.x * 256 + threadIdx.x;        // 128 blocks x 256 = 32768
    int p = idx >> 11, k = idx & (DIM - 1);
    float v = (p < 8) ? Wp[(size_t)k * 8 + p] : Wa[(size_t)k * 8 + (p - 8)];
    WpaT[idx] = f2bf(v);
}

// ---- sproj via MFMA: Z = x @ [Wp|Wa] (16-wide), fused x->bf16 emit ----
// grid 256 blocks x 256 thr (4 waves); wave handles 16 token rows.
__global__ __launch_bounds__(256) void k_sproj_mfma(const float* __restrict__ x,
                                                    const unsigned short* __restrict__ WpaT,
                                                    const float* __restrict__ bp,
                                                    const float* __restrict__ ba,
                                                    float* __restrict__ s,
                                                    unsigned short* __restrict__ xbf) {
    const int t = threadIdx.x;
    const int w = t >> 6, l = t & 63;
    const int r16 = l & 15, q = l >> 4;
    const int rowbase = blockIdx.x * 64 + w * 16;
    const float* xr = x + (size_t)(rowbase + r16) * DIM + q * 8;
    unsigned short* xw = xbf + (size_t)(rowbase + r16) * DIM + q * 8;
    const unsigned short* wrow = WpaT + r16 * DIM + q * 8;

    f32x4 acc = {};
#pragma unroll 8
    for (int ks = 0; ks < 64; ks++) {
        f32x8 xv = *(const f32x8*)(xr + ks * 32);
        ushort8 xo;
#pragma unroll
        for (int j = 0; j < 8; j++) xo[j] = f2bf(xv[j]);
        *(ushort8*)(xw + ks * 32) = xo;
        bf16x8 av = *(const bf16x8*)&xo;
        bf16x8 bv = *(const bf16x8*)(wrow + ks * 32);
        acc = __builtin_amdgcn_mfma_f32_16x16x32_bf16(av, bv, acc, 0, 0, 0);
    }
    // acc[j] = Z[rowbase + q*4 + j][col=r16]; cols 0..7 = zp, 8..15 = za
    const float bpv = bp[r16 & 7], bav = ba[r16 & 7];
#pragma unroll
    for (int j = 0; j < 4; j++) {
        float z = acc[j];
        float zo = __shfl_xor(z, 8);            // partner col r16^8
        float zp = z + bpv, za = zo + bav;
        float ph = tanhf(zp) * PI_F;
        float amp = (za > 20.f ? za : log1pf(expf(za))) + 0.1f;
        float term = (r16 < 8) ? (cosf(ph) + sinf(ph)) * amp : 0.f;
        term += __shfl_xor(term, 1);
        term += __shfl_xor(term, 2);
        term += __shfl_xor(term, 4);
        if (r16 == 0) s[rowbase + q * 4 + j] = term;
    }
}

// ---------------- 256x256 8-phase bf16 MFMA GEMM (T1+T2+T3+T4+T5) ----------------
// A: [M][2048] bf16; Bt: [2048][2048] bf16 (B^T). 512 threads = 8 waves (2M x 4N).
// LDS [slot][kh][256 rows][32 k]; 16B-unit XOR swizzle: phys_q = q ^ ((row>>1)&3).
// EPI==0 additionally reduces per-column sums of its C-tile into part[] (fused scan_partial).
__device__ __forceinline__ void stage_unit(const unsigned short* __restrict__ src,
                                           unsigned short* dst, int tid) {
    gload_lds16(src,                     dst + tid * 8);
    gload_lds16(src + (size_t)128 * DIM, dst + (tid + 512) * 8);
}

template <int EPI>
__global__ __launch_bounds__(512, 2) void k_gemm256(const unsigned short* __restrict__ A,
                                                    const unsigned short* __restrict__ Bt,
                                                    const float* __restrict__ bias,
                                                    const float* __restrict__ sc,
                                                    const float* __restrict__ resid,
                                                    float* __restrict__ C,
                                                    float* __restrict__ part) {
    __shared__ __align__(16) unsigned short As[2][2][256 * 32];
    __shared__ __align__(16) unsigned short Bs[2][2][256 * 32];
    __shared__ float colsum[2][256];
    const int tid = threadIdx.x;
    const int w = tid >> 6, lane = tid & 63;
    const int wm = w >> 2, wn = w & 3;
    const int r16 = lane & 15, q = lane >> 4;

    int bid = blockIdx.x;
    int wgs = (bid & 7) * 64 + (bid >> 3);        // bijective XCD swizzle (512 % 8 == 0)
    int tm = wgs >> 3, tn = wgs & 7;
    int brow = tm * 256, bcol = tn * 256;

    // staging source: thread tid fills phys 16B-unit 'tid' (row=tid>>2, physq=tid&3),
    // which logically holds k-chunk (tid&3) ^ ((tid>>3)&3).
    const int kq = ((tid & 3) ^ ((tid >> 3) & 3)) * 8;
    const unsigned short* pA = A  + (size_t)(brow + (tid >> 2)) * DIM + kq;
    const unsigned short* pB = Bt + (size_t)(bcol + (tid >> 2)) * DIM + kq;

    // fragment read: swizzled q (row offsets are multiples of 16 -> swizzle dep on r16 only)
    const int qs8 = (q ^ ((r16 >> 1) & 3)) * 8;
    const int offA = (wm * 128 + r16) * 32 + qs8;
    const int offB = (wn * 64  + r16) * 32 + qs8;

    f32x4 acc[8][4] = {};

    // prologue: A-K0(0), B-K0(0), A-K1(0), B-K1(0), A-K0(1) = 10 loads in flight
    stage_unit(pA,      &As[0][0][0], tid);
    stage_unit(pB,      &Bs[0][0][0], tid);
    stage_unit(pA + 32, &As[0][1][0], tid);
    stage_unit(pB + 32, &Bs[0][1][0], tid);
    stage_unit(pA + 64, &As[1][0][0], tid);
    asm volatile("s_waitcnt vmcnt(6)" ::: "memory");    // K0(0) pair landed
    __builtin_amdgcn_s_barrier();

    for (int t = 0; t < NT; ++t) {
        const int s = t & 1;
        unsigned short* A0 = &As[s][0][0];
        unsigned short* A1 = &As[s][1][0];
        unsigned short* B0 = &Bs[s][0][0];
        unsigned short* B1 = &Bs[s][1][0];
        unsigned short* nA1 = &As[s ^ 1][1][0];
        unsigned short* nB0 = &Bs[s ^ 1][0][0];
        unsigned short* nB1 = &Bs[s ^ 1][1][0];
        const unsigned short* pAn = pA + (t + 1) * 64;  // phantom tail reads stay in ws
        const unsigned short* pBn = pB + (t + 1) * 64;

        bf16x8 aF[4], bF[4];
        // ---- phase 0: (C0, K0) ----
#pragma unroll
        for (int i = 0; i < 4; i++) aF[i] = *(const bf16x8*)(A0 + offA + i * 512);
#pragma unroll
        for (int i = 0; i < 4; i++) bF[i] = *(const bf16x8*)(B0 + offB + i * 512);
        stage_unit(pBn, nB0, tid);
        __builtin_amdgcn_s_barrier();
        __builtin_amdgcn_s_setprio(1);
#pragma unroll
        for (int i = 0; i < 4; i++)
#pragma unroll
            for (int n = 0; n < 4; n++)
                acc[i][n] = __builtin_amdgcn_mfma_f32_16x16x32_bf16(aF[i], bF[n], acc[i][n], 0, 0, 0);
        __builtin_amdgcn_s_setprio(0);
        __builtin_amdgcn_s_barrier();

        // ---- phase 1: (C1, K0), B frags reused from registers ----
#pragma unroll
        for (int i = 0; i < 4; i++) aF[i] = *(const bf16x8*)(A0 + offA + 2048 + i * 512);
        stage_unit(pAn + 32, nA1, tid);
        __builtin_amdgcn_s_barrier();
        __builtin_amdgcn_s_setprio(1);
#pragma unroll
        for (int i = 0; i < 4; i++)
#pragma unroll
            for (int n = 0; n < 4; n++)
                acc[4 + i][n] = __builtin_amdgcn_mfma_f32_16x16x32_bf16(aF[i], bF[n], acc[4 + i][n], 0, 0, 0);
        __builtin_amdgcn_s_setprio(0);
        asm volatile("s_waitcnt vmcnt(6)" ::: "memory"); // K1(t) pair landed before phase 2
        __builtin_amdgcn_s_barrier();

        // ---- phase 2: (C0, K1) ----
#pragma unroll
        for (int i = 0; i < 4; i++) aF[i] = *(const bf16x8*)(A1 + offA + i * 512);
#pragma unroll
        for (int i = 0; i < 4; i++) bF[i] = *(const bf16x8*)(B1 + offB + i * 512);
        stage_unit(pBn + 32, nB1, tid);
        __builtin_amdgcn_s_barrier();
        __builtin_amdgcn_s_setprio(1);
#pragma unroll
        for (int i = 0; i < 4; i++)
#pragma unroll
            for (int n = 0; n < 4; n++)
                acc[i][n] = __builtin_amdgcn_mfma_f32_16x16x32_bf16(aF[i], bF[n], acc[i][n], 0, 0, 0);
        __builtin_amdgcn_s_setprio(0);
        __builtin_amdgcn_s_barrier();

        // ---- phase 3: (C1, K1) ----
#pragma unroll
        for (int i = 0; i < 4; i++) aF[i] = *(const bf16x8*)(A1 + offA + 2048 + i * 512);
        stage_unit(pA + (t + 2) * 64, A0, tid);          // overwrite own slot K0 (last read phase 1)
        __builtin_amdgcn_s_barrier();
        __builtin_amdgcn_s_setprio(1);
#pragma unroll
        for (int i = 0; i < 4; i++)
#pragma unroll
            for (int n = 0; n < 4; n++)
                acc[4 + i][n] = __builtin_amdgcn_mfma_f32_16x16x32_bf16(aF[i], bF[n], acc[4 + i][n], 0, 0, 0);
        __builtin_amdgcn_s_setprio(0);
        asm volatile("s_waitcnt vmcnt(6)" ::: "memory"); // K0(t+1) pair landed before next phase 0
        __builtin_amdgcn_s_barrier();
    }

    // epilogue: frag row = q*4+j, col = r16 (verified convention)
    float cs[4] = {0.f, 0.f, 0.f, 0.f};
#pragma unroll
    for (int mf = 0; mf < 8; mf++) {
        int r0 = brow + wm * 128 + mf * 16 + q * 4;
#pragma unroll
        for (int nf = 0; nf < 4; nf++) {
            int c = bcol + wn * 64 + nf * 16 + r16;
            float bc = bias[c];
#pragma unroll
            for (int j = 0; j < 4; j++) {
                int r = r0 + j;
                float v = acc[mf][nf][j] + bc;
                if (EPI == 0) { v *= sc[r]; cs[nf] += v; }
                else          v += resid[(size_t)r * DIM + c];
                C[(size_t)r * DIM + c] = v;
            }
        }
    }
    if (EPI == 0) {   // fused scan_partial: column sums of this 256x256 tile
#pragma unroll
        for (int nf = 0; nf < 4; nf++) {
            float v = cs[nf];
            v += __shfl_xor(v, 16);           // reduce over q
            v += __shfl_xor(v, 32);
            if (q == 0) colsum[wm][wn * 64 + nf * 16 + r16] = v;
        }
        __syncthreads();
        if (tid < 256)
            part[(size_t)(brow >> 8) * DIM + bcol + tid] = colsum[0][tid] + colsum[1][tid];
    }
}

// ---------------- cumsum over L: chunk-offset scan + apply ----------------
__global__ __launch_bounds__(256) void k_scan_offsets(float* __restrict__ part) {
    int tid = blockIdx.x * 256 + threadIdx.x;  // (b, d)
    int d = tid & (DIM - 1);
    int b = tid >> 11;
    float run = 0.f;
    for (int ch = 0; ch < NCH; ch++) {
        size_t idx = ((size_t)b * NCH + ch) * DIM + d;
        float v = part[idx];
        part[idx] = run;
        run += v;
    }
}

__global__ __launch_bounds__(256) void k_scan_apply(float* __restrict__ bound,
                                                    const float* __restrict__ part) {
    int tid = blockIdx.x * 256 + threadIdx.x;
    int d = tid & (DIM - 1);
    int ch = (tid >> 11) & (NCH - 1);
    int b = tid >> 15;
    float run = part[tid];
    float* p = bound + ((size_t)b * LSEQ + (size_t)ch * CHL) * DIM + d;
    for (int i = 0; i < CHL; i++) { run += p[(size_t)i * DIM]; p[(size_t)i * DIM] = run; }
}

// ---------------- LayerNorm(retrieved/64) -> h bf16 ----------------
__global__ __launch_bounds__(256) void k_lnorm(const float* __restrict__ ret,
                                               const float* __restrict__ g,
                                               const float* __restrict__ bta,
                                               unsigned short* __restrict__ h) {
    int row = blockIdx.x, t = threadIdx.x;
    const float4* r4 = (const float4*)(ret + (size_t)row * DIM);
    float4 v0 = r4[2 * t], v1 = r4[2 * t + 1];
    const float scl = 1.0f / 64.0f;   // 1/sqrt(L)
    v0.x *= scl; v0.y *= scl; v0.z *= scl; v0.w *= scl;
    v1.x *= scl; v1.y *= scl; v1.z *= scl; v1.w *= scl;
    float sum = v0.x + v0.y + v0.z + v0.w + v1.x + v1.y + v1.z + v1.w;
    float ss  = v0.x*v0.x + v0.y*v0.y + v0.z*v0.z + v0.w*v0.w
              + v1.x*v1.x + v1.y*v1.y + v1.z*v1.z + v1.w*v1.w;
#pragma unroll
    for (int off = 32; off; off >>= 1) { sum += __shfl_down(sum, off); ss += __shfl_down(ss, off); }
    __shared__ float red[4][2];
    __shared__ float mu_s, rstd_s;
    int w = t >> 6, lane = t & 63;
    if (lane == 0) { red[w][0] = sum; red[w][1] = ss; }
    __syncthreads();
    if (t == 0) {
        float S = red[0][0] + red[1][0] + red[2][0] + red[3][0];
        float Q = red[0][1] + red[1][1] + red[2][1] + red[3][1];
        float mu = S / DIM;
        float var = Q / DIM - mu * mu;
        mu_s = mu; rstd_s = rsqrtf(var + 1e-5f);
    }
    __syncthreads();
    float mu = mu_s, rstd = rstd_s;
    f32x8 gv = *(const f32x8*)(g + t * 8);
    f32x8 bv = *(const f32x8*)(bta + t * 8);
    float vv[8] = { v0.x, v0.y, v0.z, v0.w, v1.x, v1.y, v1.z, v1.w };
    ushort8 o;
#pragma unroll
    for (int j = 0; j < 8; j++) o[j] = f2bf((vv[j] - mu) * rstd * gv[j] + bv[j]);
    *(ushort8*)(h + (size_t)row * DIM + t * 8) = o;
}

extern "C" void kernel_launch(void* const* d_in, const int* in_sizes, int n_in,
                              void* d_out, int out_size, void* d_ws, size_t ws_size,
                              hipStream_t stream) {
    const float* x   = (const float*)d_in[0];
    const float* Wp  = (const float*)d_in[1];
    const float* bp  = (const float*)d_in[2];
    const float* Wa  = (const float*)d_in[3];
    const float* ba  = (const float*)d_in[4];
    const float* Wv  = (const float*)d_in[5];
    const float* bv  = (const float*)d_in[6];
    const float* lng = (const float*)d_in[7];
    const float* lnb = (const float*)d_in[8];
    const float* Wo  = (const float*)d_in[9];
    const float* bo  = (const float*)d_in[10];
    float* out = (float*)d_out;

    char* ws = (char*)d_ws;
    unsigned short* x_bf = (unsigned short*)ws; ws += (size_t)NTOK * DIM * 2;   // reused as h
    unsigned short* WvT  = (unsigned short*)ws; ws += (size_t)DIM * DIM * 2;
    unsigned short* WoT  = (unsigned short*)ws; ws += (size_t)DIM * DIM * 2;
    unsigned short* WpaT = (unsigned short*)ws; ws += (size_t)16 * DIM * 2;
    float* svec          = (float*)ws;          ws += (size_t)NTOK * 4;
    float* bound         = (float*)ws;          ws += (size_t)NTOK * DIM * 4;
    float* part          = (float*)ws;          ws += (size_t)BATCH * NCH * DIM * 4;

    dim3 tb(32, 8);
    k_transpose<<<dim3(64, 64), tb, 0, stream>>>(Wv, WvT);
    k_transpose<<<dim3(64, 64), tb, 0, stream>>>(Wo, WoT);
    k_prep_wpa<<<128, 256, 0, stream>>>(Wp, Wa, WpaT);
    k_sproj_mfma<<<NTOK / 64, 256, 0, stream>>>(x, WpaT, bp, ba, svec, x_bf);

    k_gemm256<0><<<512, 512, 0, stream>>>(x_bf, WvT, bv, svec, nullptr, bound, part);

    k_scan_offsets<<<BATCH * DIM / 256, 256, 0, stream>>>(part);
    k_scan_apply<<<BATCH * NCH * DIM / 256, 256, 0, stream>>>(bound, part);

    k_lnorm<<<NTOK, 256, 0, stream>>>(bound, lng, lnb, x_bf);   // h reuses x_bf buffer

    k_gemm256<1><<<512, 512, 0, stream>>>(x_bf, WoT, bo, nullptr, x, out, nullptr);
}